// Round 4
// baseline (35.412 us; speedup 1.0000x reference)
//
#include <hip/hip_runtime.h>

#define NBINS 256
#define NCH 3
#define BLOCK 256
#define HSIZE (NCH * NBINS)   // 768

using f4 = __attribute__((ext_vector_type(4))) float;

__global__ __launch_bounds__(BLOCK, 8) void hist_kernel(const float* __restrict__ in,
                                                        float* __restrict__ out,
                                                        int blocksPerBatch,
                                                        int floatsPerBatch,
                                                        float inv_n) {
    __shared__ unsigned int h[HSIZE];   // 3 KB, single copy

    const int tid = threadIdx.x;
    for (int i = tid; i < HSIZE; i += BLOCK) h[i] = 0u;
    __syncthreads();

    const int b     = blockIdx.x / blocksPerBatch;
    const int chunk = blockIdx.x % blocksPerBatch;
    const int chunkFloats = floatsPerBatch / blocksPerBatch;           // 12288
    const size_t baseElem = (size_t)b * floatsPerBatch + (size_t)chunk * chunkFloats;
    const f4* p = (const f4*)(in + baseElem);

    // channel of element e (global) = (baseElem + e) % 3; baseElem % 3 == 0.
    // e = (it*1024 + k*256 + tid) * 4  ->  channel base m = (it + k + tid) % 3
    const int mt = tid % 3;

    const int f4PerChunk = chunkFloats / 4;                            // 3072
    const int iters = f4PerChunk / (BLOCK * 4);                        // 3

    for (int it = 0; it < iters; ++it) {
        // 4 independent coalesced nt loads in flight (64 B / lane)
        f4 v[4];
#pragma unroll
        for (int k = 0; k < 4; ++k) {
            v[k] = __builtin_nontemporal_load(&p[(size_t)it * (BLOCK * 4) + k * BLOCK + tid]);
        }
#pragma unroll
        for (int k = 0; k < 4; ++k) {
            int m = mt + (it + k) % 3;          // (it+k)%3 is compile-time
            m = (m >= 3) ? m - 3 : m;
            int c1 = (m  == 2) ? 0 : m  + 1;
            int c2 = (c1 == 2) ? 0 : c1 + 1;
            const int cc[4] = {m, c1, c2, m};
            float vv[4] = {v[k][0], v[k][1], v[k][2], v[k][3]};
#pragma unroll
            for (int j = 0; j < 4; ++j) {
                int bin = (int)(vv[j] * 256.0f);            // v>=0: trunc == floor
                bin = bin < 0 ? 0 : (bin > NBINS - 1 ? NBINS - 1 : bin);
                atomicAdd(&h[(cc[j] << 8) + bin], 1u);
            }
        }
    }
    __syncthreads();

    // scale exactly by 2^-18, accumulate into transposed out[b][bin][c].
    // Addends are multiples of 2^-18, partial sums <= 1.0 -> float atomicAdd exact.
    float* dst = out + (size_t)b * HSIZE;
    for (int i = tid; i < HSIZE; i += BLOCK) {
        unsigned int s = h[i];
        if (s) {
            const int c   = i >> 8;
            const int bin = i & (NBINS - 1);
            atomicAdd(&dst[bin * NCH + c], (float)s * inv_n);
        }
    }
}

extern "C" void kernel_launch(void* const* d_in, const int* in_sizes, int n_in,
                              void* d_out, int out_size, void* d_ws, size_t ws_size,
                              hipStream_t stream) {
    const float* in = (const float*)d_in[0];
    float* out = (float*)d_out;

    const int floatsPerBatch = 512 * 512 * 3;        // H*W*C
    const int total = in_sizes[0];
    const int B = total / floatsPerBatch;            // 32
    const float inv_n = 1.0f / (float)(512 * 512);   // 2^-18, exact

    hipMemsetAsync(d_out, 0, (size_t)out_size * sizeof(float), stream);

    const int blocksPerBatch = 64;                   // 2048 blocks x 256 thr, 3 iters
    hist_kernel<<<B * blocksPerBatch, BLOCK, 0, stream>>>(in, out, blocksPerBatch,
                                                          floatsPerBatch, inv_n);
}

// Round 5
// 23.725 us; speedup vs baseline: 1.4926x; 1.4926x over previous
//
#include <hip/hip_runtime.h>

#define NBINS 256
#define NCH 3
#define NWAVES 4              // 256 threads / 64 lanes
#define BLOCK 256
#define HSIZE (NCH * NBINS)   // 768
#define ELEMS_PER_THREAD 12   // 3 x float4; 12 % 3 == 0 so channel is compile-time
#define BLOCKS_PER_BATCH 32

// R1's fastest hist structure, tail switched to plain partial stores (no atomics,
// no memset dependency). USE_WS=false falls back to atomic-into-out (needs memset).
template <bool USE_WS>
__global__ __launch_bounds__(BLOCK) void hist_kernel(const float* __restrict__ in,
                                                     unsigned int* __restrict__ ws,
                                                     float* __restrict__ out,
                                                     int floatsPerBatch,
                                                     float inv_n) {
    __shared__ unsigned int h[NWAVES][HSIZE];   // 12 KB

    const int tid = threadIdx.x;
    for (int i = tid; i < NWAVES * HSIZE; i += BLOCK) ((unsigned int*)h)[i] = 0u;
    __syncthreads();

    const int b     = blockIdx.x / BLOCKS_PER_BATCH;
    const int chunk = blockIdx.x % BLOCKS_PER_BATCH;
    const int chunkFloats = floatsPerBatch / BLOCKS_PER_BATCH;    // 24576
    const float* base = in + (size_t)b * floatsPerBatch + (size_t)chunk * chunkFloats;
    const int w = tid >> 6;

    const int floatsPerIter = BLOCK * ELEMS_PER_THREAD;           // 3072
    const int iters = chunkFloats / floatsPerIter;                // 8

    for (int it = 0; it < iters; ++it) {
        const float4* p = (const float4*)(base + (size_t)it * floatsPerIter
                                               + (size_t)tid * ELEMS_PER_THREAD);
        float4 v0 = p[0];
        float4 v1 = p[1];
        float4 v2 = p[2];
        float v[ELEMS_PER_THREAD] = {v0.x, v0.y, v0.z, v0.w,
                                     v1.x, v1.y, v1.z, v1.w,
                                     v2.x, v2.y, v2.z, v2.w};
#pragma unroll
        for (int j = 0; j < ELEMS_PER_THREAD; ++j) {
            int bin = (int)(v[j] * 256.0f);                 // v>=0: trunc == floor
            bin = bin < 0 ? 0 : (bin > NBINS - 1 ? NBINS - 1 : bin);
            const int c = j % NCH;                          // compile-time under unroll
            atomicAdd(&h[w][c * NBINS + bin], 1u);
        }
    }
    __syncthreads();

    if (USE_WS) {
        // plain coalesced store of this block's partial histogram
        unsigned int* dst = ws + (size_t)blockIdx.x * HSIZE;
        for (int i = tid; i < HSIZE; i += BLOCK) {
            dst[i] = h[0][i] + h[1][i] + h[2][i] + h[3][i];
        }
    } else {
        // fallback: exact float atomics into transposed, pre-zeroed out
        float* dst = out + (size_t)b * HSIZE;
        for (int i = tid; i < HSIZE; i += BLOCK) {
            unsigned int s = h[0][i] + h[1][i] + h[2][i] + h[3][i];
            if (s) {
                const int c   = i >> 8;
                const int bin = i & (NBINS - 1);
                atomicAdd(&dst[bin * NCH + c], (float)s * inv_n);
            }
        }
    }
}

// 32 blocks (one per batch) x 768 threads; tid = c*256 + bin.
// Fully coalesced reads of the 32 chunk-partials; exact u32 sum; scale by 2^-18.
__global__ __launch_bounds__(HSIZE) void reduce_kernel(const unsigned int* __restrict__ ws,
                                                       float* __restrict__ out,
                                                       float inv_n) {
    const int b = blockIdx.x;
    const int t = threadIdx.x;
    const unsigned int* p = ws + (size_t)b * BLOCKS_PER_BATCH * HSIZE + t;
    unsigned int s = 0;
#pragma unroll
    for (int ch = 0; ch < BLOCKS_PER_BATCH; ++ch) s += p[(size_t)ch * HSIZE];
    const int c   = t >> 8;
    const int bin = t & (NBINS - 1);
    out[(size_t)b * HSIZE + bin * NCH + c] = (float)s * inv_n;
}

extern "C" void kernel_launch(void* const* d_in, const int* in_sizes, int n_in,
                              void* d_out, int out_size, void* d_ws, size_t ws_size,
                              hipStream_t stream) {
    const float* in = (const float*)d_in[0];
    float* out = (float*)d_out;

    const int floatsPerBatch = 512 * 512 * 3;        // H*W*C
    const int total = in_sizes[0];
    const int B = total / floatsPerBatch;            // 32
    const float inv_n = 1.0f / (float)(512 * 512);   // 2^-18, exact

    const size_t wsNeeded = (size_t)B * BLOCKS_PER_BATCH * HSIZE * sizeof(unsigned int);

    if (ws_size >= wsNeeded) {
        unsigned int* ws = (unsigned int*)d_ws;
        hist_kernel<true><<<B * BLOCKS_PER_BATCH, BLOCK, 0, stream>>>(
            in, ws, out, floatsPerBatch, inv_n);
        reduce_kernel<<<B, HSIZE, 0, stream>>>(ws, out, inv_n);
    } else {
        hipMemsetAsync(d_out, 0, (size_t)out_size * sizeof(float), stream);
        hist_kernel<false><<<B * BLOCKS_PER_BATCH, BLOCK, 0, stream>>>(
            in, nullptr, out, floatsPerBatch, inv_n);
    }
}

// Round 6
// 23.468 us; speedup vs baseline: 1.5089x; 1.0109x over previous
//
#include <hip/hip_runtime.h>

#define NBINS 256
#define NCH 3
#define NWAVES 4              // 256 threads / 64 lanes
#define BLOCK 256
#define HSIZE (NCH * NBINS)   // 768
#define ELEMS_PER_THREAD 12   // 3 x float4; 12 % 3 == 0 so channel is compile-time
#define BLOCKS_PER_BATCH 32

// R5 structure + explicit prefetch double-buffering of the 3 float4 loads.
template <bool USE_WS>
__global__ __launch_bounds__(BLOCK) void hist_kernel(const float* __restrict__ in,
                                                     unsigned int* __restrict__ ws,
                                                     float* __restrict__ out,
                                                     int floatsPerBatch,
                                                     float inv_n) {
    __shared__ unsigned int h[NWAVES][HSIZE];   // 12 KB

    const int tid = threadIdx.x;
    for (int i = tid; i < NWAVES * HSIZE; i += BLOCK) ((unsigned int*)h)[i] = 0u;
    __syncthreads();

    const int b     = blockIdx.x / BLOCKS_PER_BATCH;
    const int chunk = blockIdx.x % BLOCKS_PER_BATCH;
    const int chunkFloats = floatsPerBatch / BLOCKS_PER_BATCH;    // 24576
    const float* base = in + (size_t)b * floatsPerBatch + (size_t)chunk * chunkFloats;
    const int w = tid >> 6;

    const int floatsPerIter = BLOCK * ELEMS_PER_THREAD;           // 3072
    const int iters = chunkFloats / floatsPerIter;                // 8 (compile-time path)

    const float4* p0 = (const float4*)(base + (size_t)tid * ELEMS_PER_THREAD);

    // prefetch iteration 0
    float4 a0 = p0[0], a1 = p0[1], a2 = p0[2];

#pragma unroll
    for (int it = 0; it < 8; ++it) {
        float4 b0, b1, b2;
        if (it + 1 < iters) {
            const float4* pn = (const float4*)((const float*)p0 + (size_t)(it + 1) * floatsPerIter);
            b0 = pn[0]; b1 = pn[1]; b2 = pn[2];   // next-iter loads in flight
        }
        float v[ELEMS_PER_THREAD] = {a0.x, a0.y, a0.z, a0.w,
                                     a1.x, a1.y, a1.z, a1.w,
                                     a2.x, a2.y, a2.z, a2.w};
#pragma unroll
        for (int j = 0; j < ELEMS_PER_THREAD; ++j) {
            int bin = (int)(v[j] * 256.0f);                 // v>=0: trunc == floor
            bin = bin < 0 ? 0 : (bin > NBINS - 1 ? NBINS - 1 : bin);
            const int c = j % NCH;                          // compile-time under unroll
            atomicAdd(&h[w][c * NBINS + bin], 1u);
        }
        a0 = b0; a1 = b1; a2 = b2;
    }
    __syncthreads();

    if (USE_WS) {
        // plain coalesced store of this block's partial histogram
        unsigned int* dst = ws + (size_t)blockIdx.x * HSIZE;
        for (int i = tid; i < HSIZE; i += BLOCK) {
            dst[i] = h[0][i] + h[1][i] + h[2][i] + h[3][i];
        }
    } else {
        // fallback: exact float atomics into transposed, pre-zeroed out
        float* dst = out + (size_t)b * HSIZE;
        for (int i = tid; i < HSIZE; i += BLOCK) {
            unsigned int s = h[0][i] + h[1][i] + h[2][i] + h[3][i];
            if (s) {
                const int c   = i >> 8;
                const int bin = i & (NBINS - 1);
                atomicAdd(&dst[bin * NCH + c], (float)s * inv_n);
            }
        }
    }
}

// 32 blocks (one per batch) x 768 threads; tid = c*256 + bin.
__global__ __launch_bounds__(HSIZE) void reduce_kernel(const unsigned int* __restrict__ ws,
                                                       float* __restrict__ out,
                                                       float inv_n) {
    const int b = blockIdx.x;
    const int t = threadIdx.x;
    const unsigned int* p = ws + (size_t)b * BLOCKS_PER_BATCH * HSIZE + t;
    unsigned int s = 0;
#pragma unroll
    for (int ch = 0; ch < BLOCKS_PER_BATCH; ++ch) s += p[(size_t)ch * HSIZE];
    const int c   = t >> 8;
    const int bin = t & (NBINS - 1);
    out[(size_t)b * HSIZE + bin * NCH + c] = (float)s * inv_n;
}

extern "C" void kernel_launch(void* const* d_in, const int* in_sizes, int n_in,
                              void* d_out, int out_size, void* d_ws, size_t ws_size,
                              hipStream_t stream) {
    const float* in = (const float*)d_in[0];
    float* out = (float*)d_out;

    const int floatsPerBatch = 512 * 512 * 3;        // H*W*C
    const int total = in_sizes[0];
    const int B = total / floatsPerBatch;            // 32
    const float inv_n = 1.0f / (float)(512 * 512);   // 2^-18, exact

    const size_t wsNeeded = (size_t)B * BLOCKS_PER_BATCH * HSIZE * sizeof(unsigned int);

    if (ws_size >= wsNeeded) {
        unsigned int* ws = (unsigned int*)d_ws;
        hist_kernel<true><<<B * BLOCKS_PER_BATCH, BLOCK, 0, stream>>>(
            in, ws, out, floatsPerBatch, inv_n);
        reduce_kernel<<<B, HSIZE, 0, stream>>>(ws, out, inv_n);
    } else {
        hipMemsetAsync(d_out, 0, (size_t)out_size * sizeof(float), stream);
        hist_kernel<false><<<B * BLOCKS_PER_BATCH, BLOCK, 0, stream>>>(
            in, nullptr, out, floatsPerBatch, inv_n);
    }
}